// Round 8
// baseline (4140.222 us; speedup 1.0000x reference)
//
#include <hip/hip_runtime.h>
#include <cstdint>
#include <cstddef>

#define S_LEN 2048
#define BATCH 64
#define ISZ   256
#define HSZ   128

// ---------------------------------------------------------------------------
// GEMM: C = A(MxK) @ W(NxK)^T (+bias)
// LAYOUT 0: C[m*N + n]   (row-major M x N)
// LAYOUT 1: C[(m/64)*N*64 + n*64 + (m%64)]   -> (s, c, b) transposed store
// ---------------------------------------------------------------------------
template<int LAYOUT>
__global__ __launch_bounds__(256)
void gemm_nt(const float* __restrict__ A, const float* __restrict__ W,
             const float* __restrict__ bias, float* __restrict__ C,
             int M, int N, int K)
{
    __shared__ float As[64][65];   // pad 65: A-reads 2-way conflict max
    __shared__ float Bs[64][68];   // pad 68: float4-aligned reads along n
    const int tid = threadIdx.x;
    const int tc = tid & 15, tr = tid >> 4;
    const int m0 = blockIdx.y * 64;
    const int n0 = blockIdx.x * 64;

    float acc[4][4] = {};

    for (int k0 = 0; k0 < K; k0 += 64) {
        // stage A tile (64 rows x 64 k), coalesced float4
        #pragma unroll
        for (int it = 0; it < 4; ++it) {
            int idx = tid + it * 256;
            int r = idx >> 4, c4 = (idx & 15) * 4;
            const float4 v = *reinterpret_cast<const float4*>(
                &A[(size_t)(m0 + r) * K + k0 + c4]);
            As[r][c4+0] = v.x; As[r][c4+1] = v.y;
            As[r][c4+2] = v.z; As[r][c4+3] = v.w;
        }
        // stage W tile transposed: Bs[k][n] = W[n0+n][k0+k]
        #pragma unroll
        for (int it = 0; it < 4; ++it) {
            int idx = tid + it * 256;
            int n = idx >> 4, k4 = (idx & 15) * 4;
            const float4 v = *reinterpret_cast<const float4*>(
                &W[(size_t)(n0 + n) * K + k0 + k4]);
            Bs[k4+0][n] = v.x; Bs[k4+1][n] = v.y;
            Bs[k4+2][n] = v.z; Bs[k4+3][n] = v.w;
        }
        __syncthreads();

        #pragma unroll
        for (int kk = 0; kk < 64; ++kk) {
            float a0 = As[tr*4+0][kk];
            float a1 = As[tr*4+1][kk];
            float a2 = As[tr*4+2][kk];
            float a3 = As[tr*4+3][kk];
            float4 b = *reinterpret_cast<const float4*>(&Bs[kk][tc*4]);
            acc[0][0] += a0*b.x; acc[0][1] += a0*b.y; acc[0][2] += a0*b.z; acc[0][3] += a0*b.w;
            acc[1][0] += a1*b.x; acc[1][1] += a1*b.y; acc[1][2] += a1*b.z; acc[1][3] += a1*b.w;
            acc[2][0] += a2*b.x; acc[2][1] += a2*b.y; acc[2][2] += a2*b.z; acc[2][3] += a2*b.w;
            acc[3][0] += a3*b.x; acc[3][1] += a3*b.y; acc[3][2] += a3*b.z; acc[3][3] += a3*b.w;
        }
        __syncthreads();
    }

    float bv[4];
    #pragma unroll
    for (int j = 0; j < 4; ++j)
        bv[j] = bias ? bias[n0 + tc*4 + j] : 0.f;

    #pragma unroll
    for (int i = 0; i < 4; ++i) {
        #pragma unroll
        for (int j = 0; j < 4; ++j) {
            float v = acc[i][j] + bv[j];
            int m = m0 + tr*4 + i;
            int n = n0 + tc*4 + j;
            if (LAYOUT == 0)
                C[(size_t)m * N + n] = v;
            else
                C[(size_t)(m >> 6) * ((size_t)N * 64) + (size_t)n * 64 + (m & 63)] = v;
        }
    }
}

// ---------------------------------------------------------------------------
// GRU recurrence: one WG per (direction, batch), 256 threads = 4 waves.
// Allocator evidence r3-r7: at (256,1) it keeps ~one 128-word array
// (r3: VGPR 208) but spills 192-word requests (r6: 112) and AGPR volatile
// reads regress (r7: 144, slower).  Fix: HALVE the demand — W_hh rows as
// PACKED bf16 pairs: 64 regs (main row) + 32 regs (n-half) = 96 words.
// Unpack per use is exact bit-ops (bf16->fp32 = shift/mask) issued as
// VOLATILE inline asm so LLVM cannot hoist them out of the t-loop and
// recreate the fp32 pressure.  h state / x gates / accumulation stay fp32;
// only W_hh is bf16 (RNE).
//   thread j <128 (waves 0-1): r-row j + n-row 256+j k[0:64)
//   thread 128+j  (waves 2-3): z-row 128+j + n-row 256+j k[64:128)
// h is wave-uniform: 2 per-lane regs broadcast via v_readlane (zero LDS in
// the matvec).  n-halves combine via LDS; raw s_barrier + lgkmcnt(0) keeps
// the x(t+1) prefetch in flight across barriers.
// ---------------------------------------------------------------------------
#define RL(v, l) __int_as_float(__builtin_amdgcn_readlane(__float_as_int(v), (l)))
// unpack packed bf16 pair -> fp32 (exact): lo16<<16, hi16 masked in place
#define ULO(d, p) asm volatile("v_lshlrev_b32 %0, 16, %1"         : "=v"(d) : "v"(p))
#define UHI(d, p) asm volatile("v_and_b32 %0, 0xffff0000, %1"     : "=v"(d) : "v"(p))

__device__ __forceinline__ unsigned short f2bf(float x)   // RNE fp32->bf16
{
    uint32_t u = __float_as_uint(x);
    u += 0x7fffu + ((u >> 16) & 1u);
    return (unsigned short)(u >> 16);
}
__device__ __forceinline__ uint32_t pk2(float lo, float hi)
{
    return (uint32_t)f2bf(lo) | ((uint32_t)f2bf(hi) << 16);
}

__global__ __launch_bounds__(256, 1)
void gru_scan(const float* __restrict__ xg_f, const float* __restrict__ xg_b,
              const float* __restrict__ whh_f, const float* __restrict__ whh_b,
              const float* __restrict__ bhh_f, const float* __restrict__ bhh_b,
              const float* __restrict__ h0,     // (2,64,128)
              float* __restrict__ outs,         // (S,64,256)
              float* __restrict__ hid_out)      // (2,64,128)
{
    const int j    = threadIdx.x;        // 0..255
    const int lane = j & 63;
    const int dir  = blockIdx.x >> 6;
    const int b    = blockIdx.x & 63;
    const bool low = (j < 128);          // waves 0,1 (wave-uniform)
    const int jj   = j & 127;

    const float* xg  = dir ? xg_b  : xg_f;
    const float* whh = dir ? whh_b : whh_f;
    const float* bhh = dir ? bhh_b : bhh_f;

    // main row j packed: wp[i] = (w[2i+1] : w[2i])
    uint32_t wp[64];
    #pragma unroll
    for (int k4 = 0; k4 < 32; ++k4) {
        float4 v = *reinterpret_cast<const float4*>(&whh[(size_t)j * 128 + k4 * 4]);
        wp[k4*2+0] = pk2(v.x, v.y);
        wp[k4*2+1] = pk2(v.z, v.w);
        asm volatile("" : "+v"(wp[k4*2+0]), "+v"(wp[k4*2+1]));
    }
    // n-row 256+jj, own k-half, packed: 32 regs
    uint32_t wnp[32];
    {
        const size_t nbase = (size_t)(256 + jj) * 128 + (low ? 0 : 64);
        #pragma unroll
        for (int k4 = 0; k4 < 16; ++k4) {
            float4 v = *reinterpret_cast<const float4*>(&whh[nbase + k4 * 4]);
            wnp[k4*2+0] = pk2(v.x, v.y);
            wnp[k4*2+1] = pk2(v.z, v.w);
            asm volatile("" : "+v"(wnp[k4*2+0]), "+v"(wnp[k4*2+1]));
        }
    }
    const float bh  = bhh[j];
    const float bhn = low ? bhh[256 + jj] : 0.f;

    __shared__ float hs[128];
    __shared__ float gz[128];    // z-gate dot (from high threads)
    __shared__ float gnh[128];   // n-gate high-half partial (from high threads)

    float hj = 0.f, xr = 0.f, xz = 0.f, xn = 0.f;
    if (low) {
        hj = h0[dir * (64*128) + b * 128 + j];
        hs[j] = hj;
        const int s0 = dir ? (S_LEN - 1) : 0;
        const float* xrow = xg + ((size_t)s0 * 64 + b) * 384;
        xr = xrow[j]; xz = xrow[j + 128]; xn = xrow[j + 256];
    }
    asm volatile("s_waitcnt lgkmcnt(0)" ::: "memory");
    __builtin_amdgcn_s_barrier();

    for (int t = 0; t < S_LEN; ++t) {
        // wave-local h copy (2 LDS reads per lane; 2-way alias = free)
        const float hv0 = hs[lane];
        const float hv1 = hs[64 + lane];

        // x(t+1) prefetch: a full step of slack, vmcnt never drained
        float pxr = 0.f, pxz = 0.f, pxn = 0.f;
        if (low && t + 1 < S_LEN) {
            const int s1 = dir ? (S_LEN - 2 - t) : (t + 1);
            const float* xrow = xg + ((size_t)s1 * 64 + b) * 384;
            pxr = xrow[j]; pxz = xrow[j + 128]; pxn = xrow[j + 256];
        }

        float a0 = 0.f, a1 = 0.f, a2 = 0.f, a3 = 0.f;  // main row
        float q0 = 0.f, q1 = 0.f;                      // n-row half
        if (low) {
            // k in [0,64): main row + n-row half, h from hv0
            #pragma unroll
            for (int k = 0; k < 64; k += 4) {
                const float s0 = RL(hv0, k+0), s1 = RL(hv0, k+1);
                const float s2 = RL(hv0, k+2), s3 = RL(hv0, k+3);
                float w0, w1, w2, w3, u0, u1, u2, u3;
                ULO(w0, wp[k/2]);     UHI(w1, wp[k/2]);
                ULO(w2, wp[k/2+1]);   UHI(w3, wp[k/2+1]);
                ULO(u0, wnp[k/2]);    UHI(u1, wnp[k/2]);
                ULO(u2, wnp[k/2+1]);  UHI(u3, wnp[k/2+1]);
                a0 = fmaf(w0, s0, a0);  q0 = fmaf(u0, s0, q0);
                a1 = fmaf(w1, s1, a1);  q1 = fmaf(u1, s1, q1);
                a2 = fmaf(w2, s2, a2);  q0 = fmaf(u2, s2, q0);
                a3 = fmaf(w3, s3, a3);  q1 = fmaf(u3, s3, q1);
            }
            // k in [64,128): main row only, h from hv1
            #pragma unroll
            for (int k = 0; k < 64; k += 4) {
                const float s0 = RL(hv1, k+0), s1 = RL(hv1, k+1);
                const float s2 = RL(hv1, k+2), s3 = RL(hv1, k+3);
                float w0, w1, w2, w3;
                ULO(w0, wp[32+k/2]);   UHI(w1, wp[32+k/2]);
                ULO(w2, wp[32+k/2+1]); UHI(w3, wp[32+k/2+1]);
                a0 = fmaf(w0, s0, a0);
                a1 = fmaf(w1, s1, a1);
                a2 = fmaf(w2, s2, a2);
                a3 = fmaf(w3, s3, a3);
            }
        } else {
            // k in [0,64): main row only, h from hv0
            #pragma unroll
            for (int k = 0; k < 64; k += 4) {
                const float s0 = RL(hv0, k+0), s1 = RL(hv0, k+1);
                const float s2 = RL(hv0, k+2), s3 = RL(hv0, k+3);
                float w0, w1, w2, w3;
                ULO(w0, wp[k/2]);     UHI(w1, wp[k/2]);
                ULO(w2, wp[k/2+1]);   UHI(w3, wp[k/2+1]);
                a0 = fmaf(w0, s0, a0);
                a1 = fmaf(w1, s1, a1);
                a2 = fmaf(w2, s2, a2);
                a3 = fmaf(w3, s3, a3);
            }
            // k in [64,128): main row + n-row half, h from hv1
            #pragma unroll
            for (int k = 0; k < 64; k += 4) {
                const float s0 = RL(hv1, k+0), s1 = RL(hv1, k+1);
                const float s2 = RL(hv1, k+2), s3 = RL(hv1, k+3);
                float w0, w1, w2, w3, u0, u1, u2, u3;
                ULO(w0, wp[32+k/2]);   UHI(w1, wp[32+k/2]);
                ULO(w2, wp[32+k/2+1]); UHI(w3, wp[32+k/2+1]);
                ULO(u0, wnp[k/2]);     UHI(u1, wnp[k/2]);
                ULO(u2, wnp[k/2+1]);   UHI(u3, wnp[k/2+1]);
                a0 = fmaf(w0, s0, a0);  q0 = fmaf(u0, s0, q0);
                a1 = fmaf(w1, s1, a1);  q1 = fmaf(u1, s1, q1);
                a2 = fmaf(w2, s2, a2);  q0 = fmaf(u2, s2, q0);
                a3 = fmaf(w3, s3, a3);  q1 = fmaf(u3, s3, q1);
            }
        }
        const float amain = (a0 + a1) + (a2 + a3) + bh;
        const float npart = q0 + q1;
        if (!low) {
            gz[jj]  = amain;        // z-dot (incl. bias)
            gnh[jj] = npart;        // n high-half partial
        }

        asm volatile("s_waitcnt lgkmcnt(0)" ::: "memory");
        __builtin_amdgcn_s_barrier();

        if (low) {
            const float hr = amain;
            const float hz = gz[j];
            const float hn = (npart + bhn) + gnh[j];
            const float r = 1.f / (1.f + __expf(-(xr + hr)));
            const float z = 1.f / (1.f + __expf(-(xz + hz)));
            const float x2 = xn + r * hn;
            const float ax = fabsf(x2);
            const float e  = __expf(-2.f * ax);
            const float nn = copysignf((1.f - e) / (1.f + e), x2);  // tanh
            const float hnew = nn + z * (hj - nn);   // (1-z)*n + z*h
            hj = hnew;
            hs[j] = hnew;
            const int s = dir ? (S_LEN - 1 - t) : t;
            outs[((size_t)s * 64 + b) * 256 + dir * 128 + j] = hnew;
            xr = pxr; xz = pxz; xn = pxn;
        }

        asm volatile("s_waitcnt lgkmcnt(0)" ::: "memory");
        __builtin_amdgcn_s_barrier();
    }

    if (low) hid_out[dir * (64*128) + b * 128 + j] = hj;
}

// ---------------------------------------------------------------------------
// Batch-axis softmax (over b, 64 lanes = one wave) + weighted partial
// reduction over a 32-step s-chunk.  logits are in (S, C, B) layout.
// ---------------------------------------------------------------------------
__global__ __launch_bounds__(256)
void attn_reduce(const float* __restrict__ lt,    // (S,256,64)
                 const float* __restrict__ outs,  // (S,64,256)
                 float* __restrict__ part)        // (64 chunks,64 b,256 c)
{
    __shared__ float ltile[64 * 64];     // [c_local][b]
    __shared__ float otile[64 * 65];     // [b][c_local] padded

    const int tid  = threadIdx.x;
    const int lane = tid & 63;           // = b
    const int wv   = tid >> 6;           // wave 0..3
    const int c0   = blockIdx.x * 64;    // channel block
    const int sc   = blockIdx.y;         // s-chunk 0..63

    float acc[16];
    #pragma unroll
    for (int i = 0; i < 16; ++i) acc[i] = 0.f;

    for (int si = 0; si < 32; ++si) {
        const int s = sc * 32 + si;

        // logits tile: 4096 contiguous floats
        const float4* src = reinterpret_cast<const float4*>(
            lt + (size_t)s * 16384 + (size_t)c0 * 64);
        #pragma unroll
        for (int i = 0; i < 4; ++i)
            reinterpret_cast<float4*>(ltile)[tid + i * 256] = src[tid + i * 256];

        // out_state tile (64 b x 64 c), coalesced along c
        #pragma unroll
        for (int i = 0; i < 4; ++i) {
            int idx = tid + i * 256;
            int bb = idx >> 4, c4 = (idx & 15) * 4;
            float4 v = *reinterpret_cast<const float4*>(
                &outs[((size_t)s * 64 + bb) * 256 + c0 + c4]);
            otile[bb*65 + c4+0] = v.x; otile[bb*65 + c4+1] = v.y;
            otile[bb*65 + c4+2] = v.z; otile[bb*65 + c4+3] = v.w;
        }
        __syncthreads();

        #pragma unroll
        for (int ci = 0; ci < 16; ++ci) {
            int c = wv * 16 + ci;
            float x = ltile[c * 64 + lane];
            float m = x;
            #pragma unroll
            for (int off = 32; off; off >>= 1)
                m = fmaxf(m, __shfl_xor(m, off));
            float e = __expf(x - m);
            float ssum = e;
            #pragma unroll
            for (int off = 32; off; off >>= 1)
                ssum += __shfl_xor(ssum, off);
            float attn = e / ssum;
            acc[ci] += attn * otile[lane * 65 + c];
        }
        __syncthreads();
    }

    #pragma unroll
    for (int ci = 0; ci < 16; ++ci) {
        int c = wv * 16 + ci;
        part[(size_t)sc * 16384 + (size_t)lane * 256 + c0 + c] = acc[ci];
    }
}

__global__ __launch_bounds__(256)
void reduce_part(const float* __restrict__ part, float* __restrict__ sent)
{
    int idx = blockIdx.x * 256 + threadIdx.x;   // 0..16383 = b*256+c
    float s = 0.f;
    for (int sc = 0; sc < 64; ++sc)
        s += part[(size_t)sc * 16384 + idx];
    sent[idx] = s;
}

// ---------------------------------------------------------------------------
extern "C" void kernel_launch(void* const* d_in, const int* in_sizes, int n_in,
                              void* d_out, int out_size, void* d_ws, size_t ws_size,
                              hipStream_t stream)
{
    const float* inp    = (const float*)d_in[0];
    const float* hid0   = (const float*)d_in[1];
    const float* w_ih_f = (const float*)d_in[2];
    const float* w_hh_f = (const float*)d_in[3];
    const float* b_ih_f = (const float*)d_in[4];
    const float* b_hh_f = (const float*)d_in[5];
    const float* w_ih_b = (const float*)d_in[6];
    const float* w_hh_b = (const float*)d_in[7];
    const float* b_ih_b = (const float*)d_in[8];
    const float* b_hh_b = (const float*)d_in[9];
    const float* attn_w = (const float*)d_in[10];
    const float* attn_b = (const float*)d_in[11];
    const float* comb_w = (const float*)d_in[12];

    float* out = (float*)d_out;   // [0,16384): sent, [16384,32768): hid_out

    char* ws = (char*)d_ws;
    const size_t XG_BYTES = (size_t)S_LEN * BATCH * 384 * 4;  // 201,326,592
    const size_t OS_BYTES = (size_t)S_LEN * BATCH * 256 * 4;  // 134,217,728
    if (ws_size < 2 * XG_BYTES + OS_BYTES) return;  // need 512 MiB scratch

    float* xg_f   = (float*)(ws);
    float* xg_b   = (float*)(ws + XG_BYTES);
    float* outs   = (float*)(ws + 2 * XG_BYTES);
    float* sa     = (float*)(ws);               // reuse xg_f (dead after scan)
    float* logits = (float*)(ws + XG_BYTES);    // reuse xg_b
    float* part   = (float*)(ws);               // reuse sa (dead after K4)

    const int M = S_LEN * BATCH;                // 131072
    dim3 blk(256);

    // K1: input-side gates, both directions
    gemm_nt<0><<<dim3(6, 2048), blk, 0, stream>>>(inp, w_ih_f, b_ih_f, xg_f, M, 384, 256);
    gemm_nt<0><<<dim3(6, 2048), blk, 0, stream>>>(inp, w_ih_b, b_ih_b, xg_b, M, 384, 256);

    // K2: sequential bidirectional GRU (128 independent WGs, 256 thr each)
    gru_scan<<<dim3(128), dim3(256), 0, stream>>>(
        xg_f, xg_b, w_hh_f, w_hh_b, b_hh_f, b_hh_b, hid0, outs, out + 16384);

    // K3: sent_annotation = out_state @ attn_w^T + attn_b
    gemm_nt<0><<<dim3(4, 2048), blk, 0, stream>>>(outs, attn_w, attn_b, sa, M, 256, 256);

    // K4: logits = sa @ comb_w^T, stored transposed (S,C,B)
    gemm_nt<1><<<dim3(4, 2048), blk, 0, stream>>>(sa, comb_w, nullptr, logits, M, 256, 256);

    // K5: softmax over batch + weighted partial sum over s-chunks
    attn_reduce<<<dim3(4, 64), blk, 0, stream>>>(logits, outs, part);

    // K6: final reduction over s-chunks -> sent
    reduce_part<<<dim3(64), blk, 0, stream>>>(part, out);
}

// Round 9
// 3683.851 us; speedup vs baseline: 1.1239x; 1.1239x over previous
//
#include <hip/hip_runtime.h>
#include <cstdint>
#include <cstddef>

#define S_LEN 2048
#define BATCH 64
#define ISZ   256
#define HSZ   128

// ---------------------------------------------------------------------------
// GEMM: C = A(MxK) @ W(NxK)^T (+bias)
// LAYOUT 0: C[m*N + n]   (row-major M x N)
// LAYOUT 1: C[(m/64)*N*64 + n*64 + (m%64)]   -> (s, c, b) transposed store
// ---------------------------------------------------------------------------
template<int LAYOUT>
__global__ __launch_bounds__(256)
void gemm_nt(const float* __restrict__ A, const float* __restrict__ W,
             const float* __restrict__ bias, float* __restrict__ C,
             int M, int N, int K)
{
    __shared__ float As[64][65];   // pad 65: A-reads 2-way conflict max
    __shared__ float Bs[64][68];   // pad 68: float4-aligned reads along n
    const int tid = threadIdx.x;
    const int tc = tid & 15, tr = tid >> 4;
    const int m0 = blockIdx.y * 64;
    const int n0 = blockIdx.x * 64;

    float acc[4][4] = {};

    for (int k0 = 0; k0 < K; k0 += 64) {
        // stage A tile (64 rows x 64 k), coalesced float4
        #pragma unroll
        for (int it = 0; it < 4; ++it) {
            int idx = tid + it * 256;
            int r = idx >> 4, c4 = (idx & 15) * 4;
            const float4 v = *reinterpret_cast<const float4*>(
                &A[(size_t)(m0 + r) * K + k0 + c4]);
            As[r][c4+0] = v.x; As[r][c4+1] = v.y;
            As[r][c4+2] = v.z; As[r][c4+3] = v.w;
        }
        // stage W tile transposed: Bs[k][n] = W[n0+n][k0+k]
        #pragma unroll
        for (int it = 0; it < 4; ++it) {
            int idx = tid + it * 256;
            int n = idx >> 4, k4 = (idx & 15) * 4;
            const float4 v = *reinterpret_cast<const float4*>(
                &W[(size_t)(n0 + n) * K + k0 + k4]);
            Bs[k4+0][n] = v.x; Bs[k4+1][n] = v.y;
            Bs[k4+2][n] = v.z; Bs[k4+3][n] = v.w;
        }
        __syncthreads();

        #pragma unroll
        for (int kk = 0; kk < 64; ++kk) {
            float a0 = As[tr*4+0][kk];
            float a1 = As[tr*4+1][kk];
            float a2 = As[tr*4+2][kk];
            float a3 = As[tr*4+3][kk];
            float4 b = *reinterpret_cast<const float4*>(&Bs[kk][tc*4]);
            acc[0][0] += a0*b.x; acc[0][1] += a0*b.y; acc[0][2] += a0*b.z; acc[0][3] += a0*b.w;
            acc[1][0] += a1*b.x; acc[1][1] += a1*b.y; acc[1][2] += a1*b.z; acc[1][3] += a1*b.w;
            acc[2][0] += a2*b.x; acc[2][1] += a2*b.y; acc[2][2] += a2*b.z; acc[2][3] += a2*b.w;
            acc[3][0] += a3*b.x; acc[3][1] += a3*b.y; acc[3][2] += a3*b.z; acc[3][3] += a3*b.w;
        }
        __syncthreads();
    }

    float bv[4];
    #pragma unroll
    for (int j = 0; j < 4; ++j)
        bv[j] = bias ? bias[n0 + tc*4 + j] : 0.f;

    #pragma unroll
    for (int i = 0; i < 4; ++i) {
        #pragma unroll
        for (int j = 0; j < 4; ++j) {
            float v = acc[i][j] + bv[j];
            int m = m0 + tr*4 + i;
            int n = n0 + tc*4 + j;
            if (LAYOUT == 0)
                C[(size_t)m * N + n] = v;
            else
                C[(size_t)(m >> 6) * ((size_t)N * 64) + (size_t)n * 64 + (m & 63)] = v;
        }
    }
}

// ---------------------------------------------------------------------------
// GRU recurrence: one WG per (direction, batch), 256 threads = 4 waves.
// Allocator envelope (r3-r8 evidence): at (256,1) it keeps at most ONE
// unconditional ~128-word fp32 array per thread (r3: VGPR 208); every
// larger/second/packed/AGPR request spilled (r4-r8).  Design inside that:
//   thread j keeps ONLY its main gate row w[128] in VGPRs
//     (j<128: r-row j; j>=128: z-row j)
//   the n-gate weight block (128x128 fp32, 64 KB) lives in LDS, rows
//     padded to 132 floats so the 64-lane ds_read_b128 column-walk maps
//     lane->bank stride 33 (conflict-free; unpadded would be 32-way)
//   thread j<128 computes n-row 256+j over k[0:64); thread 128+j over
//     k[64:128); halves combine via LDS (gnh) exactly as r6
// h is wave-uniform: 2 per-lane regs broadcast via v_readlane; each RL
// feeds the main-row FMA and (in the owning half) the n-row FMA.  The
// n-weight LDS reads are independent of the main FMA stream -> latency
// hides under it.  Raw s_barrier + lgkmcnt(0) keeps the x(t+1) global
// prefetch in flight across barriers.  All fp32 (absmax back to ~1e-4).
// ---------------------------------------------------------------------------
#define RL(v, l) __int_as_float(__builtin_amdgcn_readlane(__float_as_int(v), (l)))

__global__ __launch_bounds__(256, 1)
void gru_scan(const float* __restrict__ xg_f, const float* __restrict__ xg_b,
              const float* __restrict__ whh_f, const float* __restrict__ whh_b,
              const float* __restrict__ bhh_f, const float* __restrict__ bhh_b,
              const float* __restrict__ h0,     // (2,64,128)
              float* __restrict__ outs,         // (S,64,256)
              float* __restrict__ hid_out)      // (2,64,128)
{
    const int j    = threadIdx.x;        // 0..255
    const int lane = j & 63;
    const int dir  = blockIdx.x >> 6;
    const int b    = blockIdx.x & 63;
    const bool low = (j < 128);          // waves 0,1 (wave-uniform)
    const int jj   = j & 127;

    const float* xg  = dir ? xg_b  : xg_f;
    const float* whh = dir ? whh_b : whh_f;
    const float* bhh = dir ? bhh_b : bhh_f;

    // ---- LDS ----
    __shared__ float ns[128 * 132];   // n-gate rows, padded 132 (66 KB)
    __shared__ float hs[128];
    __shared__ float gz[128];         // z-gate dot (from high threads)
    __shared__ float gnh[128];        // n-gate high-half partial

    // stage n-gate weights (rows 256..383) into LDS, coalesced float4
    #pragma unroll
    for (int it = 0; it < 16; ++it) {
        const int idx = j + it * 256;         // 0..4095 float4s
        const int row = idx >> 5;             // /32 float4s per row
        const int c4  = (idx & 31) * 4;
        const float4 v = *reinterpret_cast<const float4*>(
            &whh[(size_t)(256 + row) * 128 + c4]);
        *reinterpret_cast<float4*>(&ns[row * 132 + c4]) = v;
    }

    // main row j in VGPRs: the single resident array (r3 envelope)
    float w[128];
    #pragma unroll
    for (int k4 = 0; k4 < 32; ++k4) {
        float4 v = *reinterpret_cast<const float4*>(&whh[(size_t)j * 128 + k4 * 4]);
        asm volatile("" : "+v"(v.x), "+v"(v.y), "+v"(v.z), "+v"(v.w));
        w[k4*4+0] = v.x; w[k4*4+1] = v.y; w[k4*4+2] = v.z; w[k4*4+3] = v.w;
    }
    const float bh  = bhh[j];
    const float bhn = low ? bhh[256 + jj] : 0.f;

    // per-thread LDS base for its n-row half (loop-invariant)
    const float* nrow = &ns[jj * 132 + (low ? 0 : 64)];

    float hj = 0.f, xr = 0.f, xz = 0.f, xn = 0.f;
    if (low) {
        hj = h0[dir * (64*128) + b * 128 + j];
        hs[j] = hj;
        const int s0 = dir ? (S_LEN - 1) : 0;
        const float* xrow = xg + ((size_t)s0 * 64 + b) * 384;
        xr = xrow[j]; xz = xrow[j + 128]; xn = xrow[j + 256];
    }
    __syncthreads();   // n-weight staging + hs must be complete

    for (int t = 0; t < S_LEN; ++t) {
        // wave-local h copy (2 LDS reads per lane; 2-way alias = free)
        const float hv0 = hs[lane];
        const float hv1 = hs[64 + lane];

        // x(t+1) prefetch: a full step of slack, vmcnt never drained
        float pxr = 0.f, pxz = 0.f, pxn = 0.f;
        if (low && t + 1 < S_LEN) {
            const int s1 = dir ? (S_LEN - 2 - t) : (t + 1);
            const float* xrow = xg + ((size_t)s1 * 64 + b) * 384;
            pxr = xrow[j]; pxz = xrow[j + 128]; pxn = xrow[j + 256];
        }

        float a0 = 0.f, a1 = 0.f, a2 = 0.f, a3 = 0.f;  // main row
        float q0 = 0.f, q1 = 0.f;                      // n-row half
        if (low) {
            // k in [0,64): main + n-half (weights from LDS), h from hv0
            #pragma unroll
            for (int k4 = 0; k4 < 16; ++k4) {
                const int k = k4 * 4;
                const float4 nv = *reinterpret_cast<const float4*>(&nrow[k]);
                const float s0 = RL(hv0, k+0), s1 = RL(hv0, k+1);
                const float s2 = RL(hv0, k+2), s3 = RL(hv0, k+3);
                a0 = fmaf(w[k+0], s0, a0);  q0 = fmaf(nv.x, s0, q0);
                a1 = fmaf(w[k+1], s1, a1);  q1 = fmaf(nv.y, s1, q1);
                a2 = fmaf(w[k+2], s2, a2);  q0 = fmaf(nv.z, s2, q0);
                a3 = fmaf(w[k+3], s3, a3);  q1 = fmaf(nv.w, s3, q1);
            }
            // k in [64,128): main only, h from hv1
            #pragma unroll
            for (int k = 0; k < 64; k += 4) {
                a0 = fmaf(w[64+k+0], RL(hv1, k+0), a0);
                a1 = fmaf(w[64+k+1], RL(hv1, k+1), a1);
                a2 = fmaf(w[64+k+2], RL(hv1, k+2), a2);
                a3 = fmaf(w[64+k+3], RL(hv1, k+3), a3);
            }
        } else {
            // k in [0,64): main only, h from hv0
            #pragma unroll
            for (int k = 0; k < 64; k += 4) {
                a0 = fmaf(w[k+0], RL(hv0, k+0), a0);
                a1 = fmaf(w[k+1], RL(hv0, k+1), a1);
                a2 = fmaf(w[k+2], RL(hv0, k+2), a2);
                a3 = fmaf(w[k+3], RL(hv0, k+3), a3);
            }
            // k in [64,128): main + n-half (weights from LDS), h from hv1
            #pragma unroll
            for (int k4 = 0; k4 < 16; ++k4) {
                const int k = k4 * 4;
                const float4 nv = *reinterpret_cast<const float4*>(&nrow[k]);
                const float s0 = RL(hv1, k+0), s1 = RL(hv1, k+1);
                const float s2 = RL(hv1, k+2), s3 = RL(hv1, k+3);
                a0 = fmaf(w[64+k+0], s0, a0);  q0 = fmaf(nv.x, s0, q0);
                a1 = fmaf(w[64+k+1], s1, a1);  q1 = fmaf(nv.y, s1, q1);
                a2 = fmaf(w[64+k+2], s2, a2);  q0 = fmaf(nv.z, s2, q0);
                a3 = fmaf(w[64+k+3], s3, a3);  q1 = fmaf(nv.w, s3, q1);
            }
        }
        const float amain = (a0 + a1) + (a2 + a3) + bh;
        const float npart = q0 + q1;
        if (!low) {
            gz[jj]  = amain;        // z-dot (incl. bias)
            gnh[jj] = npart;        // n high-half partial
        }

        asm volatile("s_waitcnt lgkmcnt(0)" ::: "memory");
        __builtin_amdgcn_s_barrier();

        if (low) {
            const float hr = amain;
            const float hz = gz[j];
            const float hn = (npart + bhn) + gnh[j];
            const float r = 1.f / (1.f + __expf(-(xr + hr)));
            const float z = 1.f / (1.f + __expf(-(xz + hz)));
            const float x2 = xn + r * hn;
            const float ax = fabsf(x2);
            const float e  = __expf(-2.f * ax);
            const float nn = copysignf((1.f - e) / (1.f + e), x2);  // tanh
            const float hnew = nn + z * (hj - nn);   // (1-z)*n + z*h
            hj = hnew;
            hs[j] = hnew;
            const int s = dir ? (S_LEN - 1 - t) : t;
            outs[((size_t)s * 64 + b) * 256 + dir * 128 + j] = hnew;
            xr = pxr; xz = pxz; xn = pxn;
        }

        asm volatile("s_waitcnt lgkmcnt(0)" ::: "memory");
        __builtin_amdgcn_s_barrier();
    }

    if (low) hid_out[dir * (64*128) + b * 128 + j] = hj;
}

// ---------------------------------------------------------------------------
// Batch-axis softmax (over b, 64 lanes = one wave) + weighted partial
// reduction over a 32-step s-chunk.  logits are in (S, C, B) layout.
// ---------------------------------------------------------------------------
__global__ __launch_bounds__(256)
void attn_reduce(const float* __restrict__ lt,    // (S,256,64)
                 const float* __restrict__ outs,  // (S,64,256)
                 float* __restrict__ part)        // (64 chunks,64 b,256 c)
{
    __shared__ float ltile[64 * 64];     // [c_local][b]
    __shared__ float otile[64 * 65];     // [b][c_local] padded

    const int tid  = threadIdx.x;
    const int lane = tid & 63;           // = b
    const int wv   = tid >> 6;           // wave 0..3
    const int c0   = blockIdx.x * 64;    // channel block
    const int sc   = blockIdx.y;         // s-chunk 0..63

    float acc[16];
    #pragma unroll
    for (int i = 0; i < 16; ++i) acc[i] = 0.f;

    for (int si = 0; si < 32; ++si) {
        const int s = sc * 32 + si;

        // logits tile: 4096 contiguous floats
        const float4* src = reinterpret_cast<const float4*>(
            lt + (size_t)s * 16384 + (size_t)c0 * 64);
        #pragma unroll
        for (int i = 0; i < 4; ++i)
            reinterpret_cast<float4*>(ltile)[tid + i * 256] = src[tid + i * 256];

        // out_state tile (64 b x 64 c), coalesced along c
        #pragma unroll
        for (int i = 0; i < 4; ++i) {
            int idx = tid + i * 256;
            int bb = idx >> 4, c4 = (idx & 15) * 4;
            float4 v = *reinterpret_cast<const float4*>(
                &outs[((size_t)s * 64 + bb) * 256 + c0 + c4]);
            otile[bb*65 + c4+0] = v.x; otile[bb*65 + c4+1] = v.y;
            otile[bb*65 + c4+2] = v.z; otile[bb*65 + c4+3] = v.w;
        }
        __syncthreads();

        #pragma unroll
        for (int ci = 0; ci < 16; ++ci) {
            int c = wv * 16 + ci;
            float x = ltile[c * 64 + lane];
            float m = x;
            #pragma unroll
            for (int off = 32; off; off >>= 1)
                m = fmaxf(m, __shfl_xor(m, off));
            float e = __expf(x - m);
            float ssum = e;
            #pragma unroll
            for (int off = 32; off; off >>= 1)
                ssum += __shfl_xor(ssum, off);
            float attn = e / ssum;
            acc[ci] += attn * otile[lane * 65 + c];
        }
        __syncthreads();
    }

    #pragma unroll
    for (int ci = 0; ci < 16; ++ci) {
        int c = wv * 16 + ci;
        part[(size_t)sc * 16384 + (size_t)lane * 256 + c0 + c] = acc[ci];
    }
}

__global__ __launch_bounds__(256)
void reduce_part(const float* __restrict__ part, float* __restrict__ sent)
{
    int idx = blockIdx.x * 256 + threadIdx.x;   // 0..16383 = b*256+c
    float s = 0.f;
    for (int sc = 0; sc < 64; ++sc)
        s += part[(size_t)sc * 16384 + idx];
    sent[idx] = s;
}

// ---------------------------------------------------------------------------
extern "C" void kernel_launch(void* const* d_in, const int* in_sizes, int n_in,
                              void* d_out, int out_size, void* d_ws, size_t ws_size,
                              hipStream_t stream)
{
    const float* inp    = (const float*)d_in[0];
    const float* hid0   = (const float*)d_in[1];
    const float* w_ih_f = (const float*)d_in[2];
    const float* w_hh_f = (const float*)d_in[3];
    const float* b_ih_f = (const float*)d_in[4];
    const float* b_hh_f = (const float*)d_in[5];
    const float* w_ih_b = (const float*)d_in[6];
    const float* w_hh_b = (const float*)d_in[7];
    const float* b_ih_b = (const float*)d_in[8];
    const float* b_hh_b = (const float*)d_in[9];
    const float* attn_w = (const float*)d_in[10];
    const float* attn_b = (const float*)d_in[11];
    const float* comb_w = (const float*)d_in[12];

    float* out = (float*)d_out;   // [0,16384): sent, [16384,32768): hid_out

    char* ws = (char*)d_ws;
    const size_t XG_BYTES = (size_t)S_LEN * BATCH * 384 * 4;  // 201,326,592
    const size_t OS_BYTES = (size_t)S_LEN * BATCH * 256 * 4;  // 134,217,728
    if (ws_size < 2 * XG_BYTES + OS_BYTES) return;  // need 512 MiB scratch

    float* xg_f   = (float*)(ws);
    float* xg_b   = (float*)(ws + XG_BYTES);
    float* outs   = (float*)(ws + 2 * XG_BYTES);
    float* sa     = (float*)(ws);               // reuse xg_f (dead after scan)
    float* logits = (float*)(ws + XG_BYTES);    // reuse xg_b
    float* part   = (float*)(ws);               // reuse sa (dead after K4)

    const int M = S_LEN * BATCH;                // 131072
    dim3 blk(256);

    // K1: input-side gates, both directions
    gemm_nt<0><<<dim3(6, 2048), blk, 0, stream>>>(inp, w_ih_f, b_ih_f, xg_f, M, 384, 256);
    gemm_nt<0><<<dim3(6, 2048), blk, 0, stream>>>(inp, w_ih_b, b_ih_b, xg_b, M, 384, 256);

    // K2: sequential bidirectional GRU (128 independent WGs, 256 thr each)
    gru_scan<<<dim3(128), dim3(256), 0, stream>>>(
        xg_f, xg_b, w_hh_f, w_hh_b, b_hh_f, b_hh_b, hid0, outs, out + 16384);

    // K3: sent_annotation = out_state @ attn_w^T + attn_b
    gemm_nt<0><<<dim3(4, 2048), blk, 0, stream>>>(outs, attn_w, attn_b, sa, M, 256, 256);

    // K4: logits = sa @ comb_w^T, stored transposed (S,C,B)
    gemm_nt<1><<<dim3(4, 2048), blk, 0, stream>>>(sa, comb_w, nullptr, logits, M, 256, 256);

    // K5: softmax over batch + weighted partial sum over s-chunks
    attn_reduce<<<dim3(4, 64), blk, 0, stream>>>(logits, outs, part);

    // K6: final reduction over s-chunks -> sent
    reduce_part<<<dim3(64), blk, 0, stream>>>(part, out);
}

// Round 10
// 2587.937 us; speedup vs baseline: 1.5998x; 1.4235x over previous
//
#include <hip/hip_runtime.h>
#include <cstdint>
#include <cstddef>

#define S_LEN 2048
#define BATCH 64
#define ISZ   256
#define HSZ   128

typedef __attribute__((ext_vector_type(8))) short short8;   // 8 bf16 = 4 VGPR
typedef __attribute__((ext_vector_type(4))) float f32x4;    // MFMA acc

// ---------------------------------------------------------------------------
// Split-precision bf16 MFMA GEMM: C = A(MxK) @ W(NxK)^T (+bias)
// A = Ah + Al (bf16 hi + bf16 residual), same for W; C ~= AhWh + AhWl + AlWh
// (lo*lo dropped, ~2^-16 relative).  Tiles: BM=128, BN=128, BK=64.
// 256 threads = 4 waves; wave w owns m-rows [w*32,(w+1)*32) x all 128 n:
// 2(m) x 8(n) 16x16 frags, K=32 per mfma -> 48 MFMA per 32-k step.
// LDS tiles row-major [row][k] stride 72 bf16 (144B: 16B-aligned rows,
// 4-bank row offset -> 2-way alias = free).  Frag = 16B contiguous k.
// LAYOUT 0: C[m*N+n];  LAYOUT 1: C[(m>>6)*N*64 + n*64 + (m&63)]  (s,c,b)
// ---------------------------------------------------------------------------
__device__ __forceinline__ uint32_t bfh(float x)   // fp32 -> bf16 bits (RNE)
{
    uint32_t u = __float_as_uint(x);
    u += 0x7fffu + ((u >> 16) & 1u);
    return u >> 16;
}

// stage a 128x64 fp32 tile as bf16 hi/lo into LDS (rows row0.., k offset k0)
__device__ __forceinline__ void stage_tile(const float* __restrict__ src, int row0,
                                           int K, int k0, int tid,
                                           short* __restrict__ hi, short* __restrict__ lo)
{
    #pragma unroll
    for (int it = 0; it < 4; ++it) {
        const int g   = tid + it * 256;      // 0..1023 groups of 8 k
        const int row = g >> 3;
        const int kg  = (g & 7) * 8;
        const float* p = src + (size_t)(row0 + row) * K + k0 + kg;
        const float4 v0 = *reinterpret_cast<const float4*>(p);
        const float4 v1 = *reinterpret_cast<const float4*>(p + 4);
        const float f[8] = {v0.x, v0.y, v0.z, v0.w, v1.x, v1.y, v1.z, v1.w};
        uint32_t hp[4], lp[4];
        #pragma unroll
        for (int i = 0; i < 4; ++i) {
            const uint32_t h0 = bfh(f[2*i]), h1 = bfh(f[2*i+1]);
            const float r0 = f[2*i]   - __uint_as_float(h0 << 16);  // exact
            const float r1 = f[2*i+1] - __uint_as_float(h1 << 16);  // exact
            hp[i] = h0 | (h1 << 16);
            lp[i] = bfh(r0) | (bfh(r1) << 16);
        }
        *reinterpret_cast<uint4*>(&hi[row*72 + kg]) = make_uint4(hp[0], hp[1], hp[2], hp[3]);
        *reinterpret_cast<uint4*>(&lo[row*72 + kg]) = make_uint4(lp[0], lp[1], lp[2], lp[3]);
    }
}

template<int LAYOUT>
__global__ __launch_bounds__(256, 2)
void gemm_mfma(const float* __restrict__ A, const float* __restrict__ W,
               const float* __restrict__ bias, float* __restrict__ C,
               int M, int N, int K)
{
    __shared__ short As_hi[128*72];
    __shared__ short As_lo[128*72];
    __shared__ short Ws_hi[128*72];
    __shared__ short Ws_lo[128*72];

    const int tid = threadIdx.x;
    const int wv  = tid >> 6;          // wave 0..3
    const int l   = tid & 63;
    const int fr  = l & 15;            // frag row (m for A, n for B)
    const int fk  = (l >> 4) * 8;      // frag k-offset within 32-k step
    const int m0  = blockIdx.y * 128;
    const int n0  = blockIdx.x * 128;

    f32x4 acc[2][8] = {};

    for (int k0 = 0; k0 < K; k0 += 64) {
        stage_tile(A, m0, K, k0, tid, As_hi, As_lo);
        stage_tile(W, n0, K, k0, tid, Ws_hi, Ws_lo);
        __syncthreads();

        #pragma unroll
        for (int ks = 0; ks < 64; ks += 32) {
            short8 ah[2], al[2], bh[8], bl[8];
            #pragma unroll
            for (int mt = 0; mt < 2; ++mt) {
                const int r = (wv*32 + mt*16 + fr) * 72 + ks + fk;
                ah[mt] = *reinterpret_cast<const short8*>(&As_hi[r]);
                al[mt] = *reinterpret_cast<const short8*>(&As_lo[r]);
            }
            #pragma unroll
            for (int nt = 0; nt < 8; ++nt) {
                const int r = (nt*16 + fr) * 72 + ks + fk;
                bh[nt] = *reinterpret_cast<const short8*>(&Ws_hi[r]);
                bl[nt] = *reinterpret_cast<const short8*>(&Ws_lo[r]);
            }
            #pragma unroll
            for (int mt = 0; mt < 2; ++mt) {
                #pragma unroll
                for (int nt = 0; nt < 8; ++nt) {
                    acc[mt][nt] = __builtin_amdgcn_mfma_f32_16x16x32_bf16(
                        ah[mt], bh[nt], acc[mt][nt], 0, 0, 0);
                    acc[mt][nt] = __builtin_amdgcn_mfma_f32_16x16x32_bf16(
                        ah[mt], bl[nt], acc[mt][nt], 0, 0, 0);
                    acc[mt][nt] = __builtin_amdgcn_mfma_f32_16x16x32_bf16(
                        al[mt], bh[nt], acc[mt][nt], 0, 0, 0);
                }
            }
        }
        __syncthreads();
    }

    // epilogue: C/D frag layout col = lane&15 (n), row = (lane>>4)*4+reg (m)
    const int orow = (l >> 4) * 4;
    #pragma unroll
    for (int nt = 0; nt < 8; ++nt) {
        const int n = n0 + nt*16 + fr;
        const float bv = bias ? bias[n] : 0.f;
        #pragma unroll
        for (int mt = 0; mt < 2; ++mt) {
            const int mbase = m0 + wv*32 + mt*16 + orow;
            const f32x4 a = acc[mt][nt];
            if (LAYOUT == 0) {
                #pragma unroll
                for (int r = 0; r < 4; ++r)
                    C[(size_t)(mbase + r) * N + n] = a[r] + bv;
            } else {
                float4 o;
                o.x = a[0] + bv; o.y = a[1] + bv; o.z = a[2] + bv; o.w = a[3] + bv;
                *reinterpret_cast<float4*>(
                    &C[(size_t)(mbase >> 6) * ((size_t)N * 64) +
                       (size_t)n * 64 + (mbase & 63)]) = o;
            }
        }
    }
}

// ---------------------------------------------------------------------------
// GRU recurrence (r6 version — best measured, 1724us): one WG per
// (direction,batch), 256 threads = 4 waves.  Thread j<128: r-row j +
// n-row 256+j k[0:64); thread 128+j: z-row 128+j + n-row 256+j k[64:128).
// h wave-uniform via v_readlane; n-halves combine via LDS.
// ---------------------------------------------------------------------------
#define RL(v, l) __int_as_float(__builtin_amdgcn_readlane(__float_as_int(v), (l)))

__global__ __launch_bounds__(256, 1)
void gru_scan(const float* __restrict__ xg_f, const float* __restrict__ xg_b,
              const float* __restrict__ whh_f, const float* __restrict__ whh_b,
              const float* __restrict__ bhh_f, const float* __restrict__ bhh_b,
              const float* __restrict__ h0,     // (2,64,128)
              float* __restrict__ outs,         // (S,64,256)
              float* __restrict__ hid_out)      // (2,64,128)
{
    const int j    = threadIdx.x;        // 0..255
    const int lane = j & 63;
    const int dir  = blockIdx.x >> 6;
    const int b    = blockIdx.x & 63;
    const bool low = (j < 128);          // waves 0,1 (wave-uniform)
    const int jj   = j & 127;

    const float* xg  = dir ? xg_b  : xg_f;
    const float* whh = dir ? whh_b : whh_f;
    const float* bhh = dir ? bhh_b : bhh_f;

    // main row j: r-gate rows 0..127 (low) / z-gate rows 128..255 (high)
    float w[128];
    #pragma unroll
    for (int k4 = 0; k4 < 32; ++k4) {
        float4 v = *reinterpret_cast<const float4*>(&whh[(size_t)j * 128 + k4 * 4]);
        asm volatile("" : "+v"(v.x), "+v"(v.y), "+v"(v.z), "+v"(v.w));
        w[k4*4+0] = v.x; w[k4*4+1] = v.y; w[k4*4+2] = v.z; w[k4*4+3] = v.w;
    }
    // n-row 256+jj, own k-half: low -> k[0:64), high -> k[64:128)
    float wn[64];
    {
        const size_t nbase = (size_t)(256 + jj) * 128 + (low ? 0 : 64);
        #pragma unroll
        for (int k4 = 0; k4 < 16; ++k4) {
            float4 v = *reinterpret_cast<const float4*>(&whh[nbase + k4 * 4]);
            asm volatile("" : "+v"(v.x), "+v"(v.y), "+v"(v.z), "+v"(v.w));
            wn[k4*4+0] = v.x; wn[k4*4+1] = v.y; wn[k4*4+2] = v.z; wn[k4*4+3] = v.w;
        }
    }
    const float bh  = bhh[j];
    const float bhn = low ? bhh[256 + jj] : 0.f;

    __shared__ float hs[128];
    __shared__ float gz[128];    // z-gate dot (from high threads)
    __shared__ float gnh[128];   // n-gate high-half partial (from high threads)

    float hj = 0.f, xr = 0.f, xz = 0.f, xn = 0.f;
    if (low) {
        hj = h0[dir * (64*128) + b * 128 + j];
        hs[j] = hj;
        const int s0 = dir ? (S_LEN - 1) : 0;
        const float* xrow = xg + ((size_t)s0 * 64 + b) * 384;
        xr = xrow[j]; xz = xrow[j + 128]; xn = xrow[j + 256];
    }
    asm volatile("s_waitcnt lgkmcnt(0)" ::: "memory");
    __builtin_amdgcn_s_barrier();

    for (int t = 0; t < S_LEN; ++t) {
        // wave-local h copy (2 LDS reads per lane; 2-way alias = free)
        const float hv0 = hs[lane];
        const float hv1 = hs[64 + lane];

        // x(t+1) prefetch: a full step of slack, vmcnt never drained
        float pxr = 0.f, pxz = 0.f, pxn = 0.f;
        if (low && t + 1 < S_LEN) {
            const int s1 = dir ? (S_LEN - 2 - t) : (t + 1);
            const float* xrow = xg + ((size_t)s1 * 64 + b) * 384;
            pxr = xrow[j]; pxz = xrow[j + 128]; pxn = xrow[j + 256];
        }

        float a0 = 0.f, a1 = 0.f, a2 = 0.f, a3 = 0.f;  // main row
        float q0 = 0.f, q1 = 0.f;                      // n-row half
        if (low) {
            #pragma unroll
            for (int k = 0; k < 64; k += 4) {
                const float s0 = RL(hv0, k+0), s1 = RL(hv0, k+1);
                const float s2 = RL(hv0, k+2), s3 = RL(hv0, k+3);
                a0 = fmaf(w[k+0], s0, a0);  q0 = fmaf(wn[k+0], s0, q0);
                a1 = fmaf(w[k+1], s1, a1);  q1 = fmaf(wn[k+1], s1, q1);
                a2 = fmaf(w[k+2], s2, a2);  q0 = fmaf(wn[k+2], s2, q0);
                a3 = fmaf(w[k+3], s3, a3);  q1 = fmaf(wn[k+3], s3, q1);
            }
            #pragma unroll
            for (int k = 0; k < 64; k += 4) {
                a0 = fmaf(w[64+k+0], RL(hv1, k+0), a0);
                a1 = fmaf(w[64+k+1], RL(hv1, k+1), a1);
                a2 = fmaf(w[64+k+2], RL(hv1, k+2), a2);
                a3 = fmaf(w[64+k+3], RL(hv1, k+3), a3);
            }
        } else {
            #pragma unroll
            for (int k = 0; k < 64; k += 4) {
                a0 = fmaf(w[k+0], RL(hv0, k+0), a0);
                a1 = fmaf(w[k+1], RL(hv0, k+1), a1);
                a2 = fmaf(w[k+2], RL(hv0, k+2), a2);
                a3 = fmaf(w[k+3], RL(hv0, k+3), a3);
            }
            #pragma unroll
            for (int k = 0; k < 64; k += 4) {
                const float s0 = RL(hv1, k+0), s1 = RL(hv1, k+1);
                const float s2 = RL(hv1, k+2), s3 = RL(hv1, k+3);
                a0 = fmaf(w[64+k+0], s0, a0);  q0 = fmaf(wn[k+0], s0, q0);
                a1 = fmaf(w[64+k+1], s1, a1);  q1 = fmaf(wn[k+1], s1, q1);
                a2 = fmaf(w[64+k+2], s2, a2);  q0 = fmaf(wn[k+2], s2, q0);
                a3 = fmaf(w[64+k+3], s3, a3);  q1 = fmaf(wn[k+3], s3, q1);
            }
        }
        const float amain = (a0 + a1) + (a2 + a3) + bh;
        const float npart = q0 + q1;
        if (!low) {
            gz[jj]  = amain;        // z-dot (incl. bias)
            gnh[jj] = npart;        // n high-half partial
        }

        asm volatile("s_waitcnt lgkmcnt(0)" ::: "memory");
        __builtin_amdgcn_s_barrier();

        if (low) {
            const float hr = amain;
            const float hz = gz[j];
            const float hn = (npart + bhn) + gnh[j];
            const float r = 1.f / (1.f + __expf(-(xr + hr)));
            const float z = 1.f / (1.f + __expf(-(xz + hz)));
            const float x2 = xn + r * hn;
            const float ax = fabsf(x2);
            const float e  = __expf(-2.f * ax);
            const float nn = copysignf((1.f - e) / (1.f + e), x2);  // tanh
            const float hnew = nn + z * (hj - nn);   // (1-z)*n + z*h
            hj = hnew;
            hs[j] = hnew;
            const int s = dir ? (S_LEN - 1 - t) : t;
            outs[((size_t)s * 64 + b) * 256 + dir * 128 + j] = hnew;
            xr = pxr; xz = pxz; xn = pxn;
        }

        asm volatile("s_waitcnt lgkmcnt(0)" ::: "memory");
        __builtin_amdgcn_s_barrier();
    }

    if (low) hid_out[dir * (64*128) + b * 128 + j] = hj;
}

// ---------------------------------------------------------------------------
// Batch-axis softmax (over b, 64 lanes = one wave) + weighted partial
// reduction over a 32-step s-chunk.  logits are in (S, C, B) layout.
// ---------------------------------------------------------------------------
__global__ __launch_bounds__(256)
void attn_reduce(const float* __restrict__ lt,    // (S,256,64)
                 const float* __restrict__ outs,  // (S,64,256)
                 float* __restrict__ part)        // (64 chunks,64 b,256 c)
{
    __shared__ float ltile[64 * 64];     // [c_local][b]
    __shared__ float otile[64 * 65];     // [b][c_local] padded

    const int tid  = threadIdx.x;
    const int lane = tid & 63;           // = b
    const int wv   = tid >> 6;           // wave 0..3
    const int c0   = blockIdx.x * 64;    // channel block
    const int sc   = blockIdx.y;         // s-chunk 0..63

    float acc[16];
    #pragma unroll
    for (int i = 0; i < 16; ++i) acc[i] = 0.f;

    for (int si = 0; si < 32; ++si) {
        const int s = sc * 32 + si;

        // logits tile: 4096 contiguous floats
        const float4* src = reinterpret_cast<const float4*>(
            lt + (size_t)s * 16384 + (size_t)c0 * 64);
        #pragma unroll
        for (int i = 0; i < 4; ++i)
            reinterpret_cast<float4*>(ltile)[tid + i * 256] = src[tid + i * 256];

        // out_state tile (64 b x 64 c), coalesced along c
        #pragma unroll
        for (int i = 0; i < 4; ++i) {
            int idx = tid + i * 256;
            int bb = idx >> 4, c4 = (idx & 15) * 4;
            float4 v = *reinterpret_cast<const float4*>(
                &outs[((size_t)s * 64 + bb) * 256 + c0 + c4]);
            otile[bb*65 + c4+0] = v.x; otile[bb*65 + c4+1] = v.y;
            otile[bb*65 + c4+2] = v.z; otile[bb*65 + c4+3] = v.w;
        }
        __syncthreads();

        #pragma unroll
        for (int ci = 0; ci < 16; ++ci) {
            int c = wv * 16 + ci;
            float x = ltile[c * 64 + lane];
            float m = x;
            #pragma unroll
            for (int off = 32; off; off >>= 1)
                m = fmaxf(m, __shfl_xor(m, off));
            float e = __expf(x - m);
            float ssum = e;
            #pragma unroll
            for (int off = 32; off; off >>= 1)
                ssum += __shfl_xor(ssum, off);
            float attn = e / ssum;
            acc[ci] += attn * otile[lane * 65 + c];
        }
        __syncthreads();
    }

    #pragma unroll
    for (int ci = 0; ci < 16; ++ci) {
        int c = wv * 16 + ci;
        part[(size_t)sc * 16384 + (size_t)lane * 256 + c0 + c] = acc[ci];
    }
}

__global__ __launch_bounds__(256)
void reduce_part(const float* __restrict__ part, float* __restrict__ sent)
{
    int idx = blockIdx.x * 256 + threadIdx.x;   // 0..16383 = b*256+c
    float s = 0.f;
    for (int sc = 0; sc < 64; ++sc)
        s += part[(size_t)sc * 16384 + idx];
    sent[idx] = s;
}

// ---------------------------------------------------------------------------
extern "C" void kernel_launch(void* const* d_in, const int* in_sizes, int n_in,
                              void* d_out, int out_size, void* d_ws, size_t ws_size,
                              hipStream_t stream)
{
    const float* inp    = (const float*)d_in[0];
    const float* hid0   = (const float*)d_in[1];
    const float* w_ih_f = (const float*)d_in[2];
    const float* w_hh_f = (const float*)d_in[3];
    const float* b_ih_f = (const float*)d_in[4];
    const float* b_hh_f = (const float*)d_in[5];
    const float* w_ih_b = (const float*)d_in[6];
    const float* w_hh_b = (const float*)d_in[7];
    const float* b_ih_b = (const float*)d_in[8];
    const float* b_hh_b = (const float*)d_in[9];
    const float* attn_w = (const float*)d_in[10];
    const float* attn_b = (const float*)d_in[11];
    const float* comb_w = (const float*)d_in[12];

    float* out = (float*)d_out;   // [0,16384): sent, [16384,32768): hid_out

    char* ws = (char*)d_ws;
    const size_t XG_BYTES = (size_t)S_LEN * BATCH * 384 * 4;  // 201,326,592
    const size_t OS_BYTES = (size_t)S_LEN * BATCH * 256 * 4;  // 134,217,728
    if (ws_size < 2 * XG_BYTES + OS_BYTES) return;  // need 512 MiB scratch

    float* xg_f   = (float*)(ws);
    float* xg_b   = (float*)(ws + XG_BYTES);
    float* outs   = (float*)(ws + 2 * XG_BYTES);
    float* sa     = (float*)(ws);               // reuse xg_f (dead after scan)
    float* logits = (float*)(ws + XG_BYTES);    // reuse xg_b
    float* part   = (float*)(ws);               // reuse sa (dead after K4)

    const int M = S_LEN * BATCH;                // 131072
    dim3 blk(256);

    // K1: input-side gates, both directions (MFMA split-bf16)
    gemm_mfma<0><<<dim3(3, 1024), blk, 0, stream>>>(inp, w_ih_f, b_ih_f, xg_f, M, 384, 256);
    gemm_mfma<0><<<dim3(3, 1024), blk, 0, stream>>>(inp, w_ih_b, b_ih_b, xg_b, M, 384, 256);

    // K2: sequential bidirectional GRU (128 independent WGs, 256 thr each)
    gru_scan<<<dim3(128), dim3(256), 0, stream>>>(
        xg_f, xg_b, w_hh_f, w_hh_b, b_hh_f, b_hh_b, hid0, outs, out + 16384);

    // K3: sent_annotation = out_state @ attn_w^T + attn_b (MFMA)
    gemm_mfma<0><<<dim3(2, 1024), blk, 0, stream>>>(outs, attn_w, attn_b, sa, M, 256, 256);

    // K4: logits = sa @ comb_w^T, stored transposed (S,C,B) (MFMA)
    gemm_mfma<1><<<dim3(2, 1024), blk, 0, stream>>>(sa, comb_w, nullptr, logits, M, 256, 256);

    // K5: softmax over batch + weighted partial sum over s-chunks
    attn_reduce<<<dim3(4, 64), blk, 0, stream>>>(logits, outs, part);

    // K6: final reduction over s-chunks -> sent
    reduce_part<<<dim3(64), blk, 0, stream>>>(part, out);
}

// Round 11
// 2574.435 us; speedup vs baseline: 1.6082x; 1.0052x over previous
//
#include <hip/hip_runtime.h>
#include <cstdint>
#include <cstddef>

#define S_LEN 2048
#define BATCH 64
#define ISZ   256
#define HSZ   128

typedef __attribute__((ext_vector_type(8))) short short8;   // 8 bf16 = 4 VGPR
typedef __attribute__((ext_vector_type(4))) float f32x4;    // MFMA acc

// ---------------------------------------------------------------------------
// Split-precision bf16 MFMA GEMM: C = A(MxK) @ W(NxK)^T (+bias)
// A = Ah + Al (bf16 hi + bf16 residual), same for W; C ~= AhWh + AhWl + AlWh
// (lo*lo dropped, ~2^-16 relative).  Tiles: BM=128, BN=128, BK=64.
// 256 threads = 4 waves; wave w owns m-rows [w*32,(w+1)*32) x all 128 n:
// 2(m) x 8(n) 16x16 frags, K=32 per mfma -> 48 MFMA per 32-k step.
// LDS tiles row-major [row][k] stride 72 bf16 (144B: 16B-aligned rows,
// 4-bank row offset -> 2-way alias = free).  Frag = 16B contiguous k.
// LAYOUT 0: C[m*N+n];  LAYOUT 1: C[(m>>6)*N*64 + n*64 + (m&63)]  (s,c,b)
// ---------------------------------------------------------------------------
__device__ __forceinline__ uint32_t bfh(float x)   // fp32 -> bf16 bits (RNE)
{
    uint32_t u = __float_as_uint(x);
    u += 0x7fffu + ((u >> 16) & 1u);
    return u >> 16;
}

// stage a 128x64 fp32 tile as bf16 hi/lo into LDS (rows row0.., k offset k0)
__device__ __forceinline__ void stage_tile(const float* __restrict__ src, int row0,
                                           int K, int k0, int tid,
                                           short* __restrict__ hi, short* __restrict__ lo)
{
    #pragma unroll
    for (int it = 0; it < 4; ++it) {
        const int g   = tid + it * 256;      // 0..1023 groups of 8 k
        const int row = g >> 3;
        const int kg  = (g & 7) * 8;
        const float* p = src + (size_t)(row0 + row) * K + k0 + kg;
        const float4 v0 = *reinterpret_cast<const float4*>(p);
        const float4 v1 = *reinterpret_cast<const float4*>(p + 4);
        const float f[8] = {v0.x, v0.y, v0.z, v0.w, v1.x, v1.y, v1.z, v1.w};
        uint32_t hp[4], lp[4];
        #pragma unroll
        for (int i = 0; i < 4; ++i) {
            const uint32_t h0 = bfh(f[2*i]), h1 = bfh(f[2*i+1]);
            const float r0 = f[2*i]   - __uint_as_float(h0 << 16);  // exact
            const float r1 = f[2*i+1] - __uint_as_float(h1 << 16);  // exact
            hp[i] = h0 | (h1 << 16);
            lp[i] = bfh(r0) | (bfh(r1) << 16);
        }
        *reinterpret_cast<uint4*>(&hi[row*72 + kg]) = make_uint4(hp[0], hp[1], hp[2], hp[3]);
        *reinterpret_cast<uint4*>(&lo[row*72 + kg]) = make_uint4(lp[0], lp[1], lp[2], lp[3]);
    }
}

template<int LAYOUT>
__global__ __launch_bounds__(256, 2)
void gemm_mfma(const float* __restrict__ A, const float* __restrict__ W,
               const float* __restrict__ bias, float* __restrict__ C,
               int M, int N, int K)
{
    __shared__ short As_hi[128*72];
    __shared__ short As_lo[128*72];
    __shared__ short Ws_hi[128*72];
    __shared__ short Ws_lo[128*72];

    const int tid = threadIdx.x;
    const int wv  = tid >> 6;          // wave 0..3
    const int l   = tid & 63;
    const int fr  = l & 15;            // frag row (m for A, n for B)
    const int fk  = (l >> 4) * 8;      // frag k-offset within 32-k step
    const int m0  = blockIdx.y * 128;
    const int n0  = blockIdx.x * 128;

    f32x4 acc[2][8] = {};

    for (int k0 = 0; k0 < K; k0 += 64) {
        stage_tile(A, m0, K, k0, tid, As_hi, As_lo);
        stage_tile(W, n0, K, k0, tid, Ws_hi, Ws_lo);
        __syncthreads();

        #pragma unroll
        for (int ks = 0; ks < 64; ks += 32) {
            short8 ah[2], al[2], bh[8], bl[8];
            #pragma unroll
            for (int mt = 0; mt < 2; ++mt) {
                const int r = (wv*32 + mt*16 + fr) * 72 + ks + fk;
                ah[mt] = *reinterpret_cast<const short8*>(&As_hi[r]);
                al[mt] = *reinterpret_cast<const short8*>(&As_lo[r]);
            }
            #pragma unroll
            for (int nt = 0; nt < 8; ++nt) {
                const int r = (nt*16 + fr) * 72 + ks + fk;
                bh[nt] = *reinterpret_cast<const short8*>(&Ws_hi[r]);
                bl[nt] = *reinterpret_cast<const short8*>(&Ws_lo[r]);
            }
            #pragma unroll
            for (int mt = 0; mt < 2; ++mt) {
                #pragma unroll
                for (int nt = 0; nt < 8; ++nt) {
                    acc[mt][nt] = __builtin_amdgcn_mfma_f32_16x16x32_bf16(
                        ah[mt], bh[nt], acc[mt][nt], 0, 0, 0);
                    acc[mt][nt] = __builtin_amdgcn_mfma_f32_16x16x32_bf16(
                        ah[mt], bl[nt], acc[mt][nt], 0, 0, 0);
                    acc[mt][nt] = __builtin_amdgcn_mfma_f32_16x16x32_bf16(
                        al[mt], bh[nt], acc[mt][nt], 0, 0, 0);
                }
            }
        }
        __syncthreads();
    }

    // epilogue: C/D frag layout col = lane&15 (n), row = (lane>>4)*4+reg (m)
    const int orow = (l >> 4) * 4;
    #pragma unroll
    for (int nt = 0; nt < 8; ++nt) {
        const int n = n0 + nt*16 + fr;
        const float bv = bias ? bias[n] : 0.f;
        #pragma unroll
        for (int mt = 0; mt < 2; ++mt) {
            const int mbase = m0 + wv*32 + mt*16 + orow;
            const f32x4 a = acc[mt][nt];
            if (LAYOUT == 0) {
                #pragma unroll
                for (int r = 0; r < 4; ++r)
                    C[(size_t)(mbase + r) * N + n] = a[r] + bv;
            } else {
                float4 o;
                o.x = a[0] + bv; o.y = a[1] + bv; o.z = a[2] + bv; o.w = a[3] + bv;
                *reinterpret_cast<float4*>(
                    &C[(size_t)(mbase >> 6) * ((size_t)N * 64) +
                       (size_t)n * 64 + (mbase & 63)]) = o;
            }
        }
    }
}

// ---------------------------------------------------------------------------
// GRU recurrence: one WG per (direction, batch), 256 threads = 4 waves.
// r6 partition (best measured structure):
//   thread j <128 (waves 0-1): r-row j + n-row 256+j k[0:64)
//   thread 128+j  (waves 2-3): z-row 128+j + n-row 256+j k[64:128)
// Weight storage (r8 numerics + r10 scheduling lesson): PACKED bf16 —
// wp[64] main row + wnp[32] n-half = 96 words (vs 192 fp32).  Unpack at
// use is plain C bit-ops (p<<16 / p&0xffff0000), NO volatile: the compiler
// can schedule/rematerialize freely (r8's volatile unpacks serialized the
// pipe).  If the packed arrays spill, the streamed bytes are half of r6's
// fp32 spill (384B vs 512B/thread/step) and reloads coalesce to dwordx4;
// if they stay resident (96 words is near the r6-proven 112-VGPR budget)
// the loop is pure VALU.  h stays fp32 (wave-uniform readlane broadcast);
// n-halves combine via LDS; raw s_barrier + lgkmcnt(0) keeps the x(t+1)
// prefetch in flight across barriers.
// ---------------------------------------------------------------------------
#define RL(v, l) __int_as_float(__builtin_amdgcn_readlane(__float_as_int(v), (l)))

__device__ __forceinline__ unsigned short f2bf(float x)   // RNE fp32->bf16
{
    uint32_t u = __float_as_uint(x);
    u += 0x7fffu + ((u >> 16) & 1u);
    return (unsigned short)(u >> 16);
}
__device__ __forceinline__ uint32_t pk2(float lo, float hi)
{
    return (uint32_t)f2bf(lo) | ((uint32_t)f2bf(hi) << 16);
}
// unpack (exact): elem 2i = p<<16, elem 2i+1 = p & 0xffff0000
__device__ __forceinline__ float ulo(uint32_t p) { return __uint_as_float(p << 16); }
__device__ __forceinline__ float uhi(uint32_t p) { return __uint_as_float(p & 0xffff0000u); }

__global__ __launch_bounds__(256, 1)
void gru_scan(const float* __restrict__ xg_f, const float* __restrict__ xg_b,
              const float* __restrict__ whh_f, const float* __restrict__ whh_b,
              const float* __restrict__ bhh_f, const float* __restrict__ bhh_b,
              const float* __restrict__ h0,     // (2,64,128)
              float* __restrict__ outs,         // (S,64,256)
              float* __restrict__ hid_out)      // (2,64,128)
{
    const int j    = threadIdx.x;        // 0..255
    const int lane = j & 63;
    const int dir  = blockIdx.x >> 6;
    const int b    = blockIdx.x & 63;
    const bool low = (j < 128);          // waves 0,1 (wave-uniform)
    const int jj   = j & 127;

    const float* xg  = dir ? xg_b  : xg_f;
    const float* whh = dir ? whh_b : whh_f;
    const float* bhh = dir ? bhh_b : bhh_f;

    // main row j packed bf16: wp[i] = (w[2i+1] : w[2i])
    uint32_t wp[64];
    #pragma unroll
    for (int k4 = 0; k4 < 32; ++k4) {
        float4 v = *reinterpret_cast<const float4*>(&whh[(size_t)j * 128 + k4 * 4]);
        wp[k4*2+0] = pk2(v.x, v.y);
        wp[k4*2+1] = pk2(v.z, v.w);
    }
    // n-row 256+jj, own k-half packed: 32 words
    uint32_t wnp[32];
    {
        const size_t nbase = (size_t)(256 + jj) * 128 + (low ? 0 : 64);
        #pragma unroll
        for (int k4 = 0; k4 < 16; ++k4) {
            float4 v = *reinterpret_cast<const float4*>(&whh[nbase + k4 * 4]);
            wnp[k4*2+0] = pk2(v.x, v.y);
            wnp[k4*2+1] = pk2(v.z, v.w);
        }
    }
    // pin packed arrays as materialized-before-loop (non-volatile: the
    // compiler may still schedule, but cannot sink the packing into the loop)
    #pragma unroll
    for (int i = 0; i < 64; ++i) asm("" : "+v"(wp[i]));
    #pragma unroll
    for (int i = 0; i < 32; ++i) asm("" : "+v"(wnp[i]));

    const float bh  = bhh[j];
    const float bhn = low ? bhh[256 + jj] : 0.f;

    __shared__ float hs[128];
    __shared__ float gz[128];    // z-gate dot (from high threads)
    __shared__ float gnh[128];   // n-gate high-half partial (from high threads)

    float hj = 0.f, xr = 0.f, xz = 0.f, xn = 0.f;
    if (low) {
        hj = h0[dir * (64*128) + b * 128 + j];
        hs[j] = hj;
        const int s0 = dir ? (S_LEN - 1) : 0;
        const float* xrow = xg + ((size_t)s0 * 64 + b) * 384;
        xr = xrow[j]; xz = xrow[j + 128]; xn = xrow[j + 256];
    }
    asm volatile("s_waitcnt lgkmcnt(0)" ::: "memory");
    __builtin_amdgcn_s_barrier();

    for (int t = 0; t < S_LEN; ++t) {
        // wave-local h copy (2 LDS reads per lane; 2-way alias = free)
        const float hv0 = hs[lane];
        const float hv1 = hs[64 + lane];

        // x(t+1) prefetch: a full step of slack, vmcnt never drained
        float pxr = 0.f, pxz = 0.f, pxn = 0.f;
        if (low && t + 1 < S_LEN) {
            const int s1 = dir ? (S_LEN - 2 - t) : (t + 1);
            const float* xrow = xg + ((size_t)s1 * 64 + b) * 384;
            pxr = xrow[j]; pxz = xrow[j + 128]; pxn = xrow[j + 256];
        }

        float a0 = 0.f, a1 = 0.f, a2 = 0.f, a3 = 0.f;  // main row
        float q0 = 0.f, q1 = 0.f;                      // n-row half
        if (low) {
            // k in [0,64): main + n-half, h from hv0
            #pragma unroll
            for (int k = 0; k < 64; k += 4) {
                const uint32_t p0 = wp[k/2],  p1 = wp[k/2+1];
                const uint32_t n0p = wnp[k/2], n1p = wnp[k/2+1];
                const float s0 = RL(hv0, k+0), s1 = RL(hv0, k+1);
                const float s2 = RL(hv0, k+2), s3 = RL(hv0, k+3);
                a0 = fmaf(ulo(p0), s0, a0);  q0 = fmaf(ulo(n0p), s0, q0);
                a1 = fmaf(uhi(p0), s1, a1);  q1 = fmaf(uhi(n0p), s1, q1);
                a2 = fmaf(ulo(p1), s2, a2);  q0 = fmaf(ulo(n1p), s2, q0);
                a3 = fmaf(uhi(p1), s3, a3);  q1 = fmaf(uhi(n1p), s3, q1);
            }
            // k in [64,128): main only, h from hv1
            #pragma unroll
            for (int k = 0; k < 64; k += 4) {
                const uint32_t p0 = wp[32+k/2], p1 = wp[32+k/2+1];
                a0 = fmaf(ulo(p0), RL(hv1, k+0), a0);
                a1 = fmaf(uhi(p0), RL(hv1, k+1), a1);
                a2 = fmaf(ulo(p1), RL(hv1, k+2), a2);
                a3 = fmaf(uhi(p1), RL(hv1, k+3), a3);
            }
        } else {
            // k in [0,64): main only, h from hv0
            #pragma unroll
            for (int k = 0; k < 64; k += 4) {
                const uint32_t p0 = wp[k/2], p1 = wp[k/2+1];
                a0 = fmaf(ulo(p0), RL(hv0, k+0), a0);
                a1 = fmaf(uhi(p0), RL(hv0, k+1), a1);
                a2 = fmaf(ulo(p1), RL(hv0, k+2), a2);
                a3 = fmaf(uhi(p1), RL(hv0, k+3), a3);
            }
            // k in [64,128): main + n-half, h from hv1
            #pragma unroll
            for (int k = 0; k < 64; k += 4) {
                const uint32_t p0 = wp[32+k/2], p1 = wp[32+k/2+1];
                const uint32_t n0p = wnp[k/2],  n1p = wnp[k/2+1];
                const float s0 = RL(hv1, k+0), s1 = RL(hv1, k+1);
                const float s2 = RL(hv1, k+2), s3 = RL(hv1, k+3);
                a0 = fmaf(ulo(p0), s0, a0);  q0 = fmaf(ulo(n0p), s0, q0);
                a1 = fmaf(uhi(p0), s1, a1);  q1 = fmaf(uhi(n0p), s1, q1);
                a2 = fmaf(ulo(p1), s2, a2);  q0 = fmaf(ulo(n1p), s2, q0);
                a3 = fmaf(uhi(p1), s3, a3);  q1 = fmaf(uhi(n1p), s3, q1);
            }
        }
        const float amain = (a0 + a1) + (a2 + a3) + bh;
        const float npart = q0 + q1;
        if (!low) {
            gz[jj]  = amain;        // z-dot (incl. bias)
            gnh[jj] = npart;        // n high-half partial
        }

        asm volatile("s_waitcnt lgkmcnt(0)" ::: "memory");
        __builtin_amdgcn_s_barrier();

        if (low) {
            const float hr = amain;
            const float hz = gz[j];
            const float hn = (npart + bhn) + gnh[j];
            const float r = 1.f / (1.f + __expf(-(xr + hr)));
            const float z = 1.f / (1.f + __expf(-(xz + hz)));
            const float x2 = xn + r * hn;
            const float ax = fabsf(x2);
            const float e  = __expf(-2.f * ax);
            const float nn = copysignf((1.f - e) / (1.f + e), x2);  // tanh
            const float hnew = nn + z * (hj - nn);   // (1-z)*n + z*h
            hj = hnew;
            hs[j] = hnew;
            const int s = dir ? (S_LEN - 1 - t) : t;
            outs[((size_t)s * 64 + b) * 256 + dir * 128 + j] = hnew;
            xr = pxr; xz = pxz; xn = pxn;
        }

        asm volatile("s_waitcnt lgkmcnt(0)" ::: "memory");
        __builtin_amdgcn_s_barrier();
    }

    if (low) hid_out[dir * (64*128) + b * 128 + j] = hj;
}

// ---------------------------------------------------------------------------
// Batch-axis softmax (over b, 64 lanes = one wave) + weighted partial
// reduction over a 32-step s-chunk.  logits are in (S, C, B) layout.
// ---------------------------------------------------------------------------
__global__ __launch_bounds__(256)
void attn_reduce(const float* __restrict__ lt,    // (S,256,64)
                 const float* __restrict__ outs,  // (S,64,256)
                 float* __restrict__ part)        // (64 chunks,64 b,256 c)
{
    __shared__ float ltile[64 * 64];     // [c_local][b]
    __shared__ float otile[64 * 65];     // [b][c_local] padded

    const int tid  = threadIdx.x;
    const int lane = tid & 63;           // = b
    const int wv   = tid >> 6;           // wave 0..3
    const int c0   = blockIdx.x * 64;    // channel block
    const int sc   = blockIdx.y;         // s-chunk 0..63

    float acc[16];
    #pragma unroll
    for (int i = 0; i < 16; ++i) acc[i] = 0.f;

    for (int si = 0; si < 32; ++si) {
        const int s = sc * 32 + si;

        // logits tile: 4096 contiguous floats
        const float4* src = reinterpret_cast<const float4*>(
            lt + (size_t)s * 16384 + (size_t)c0 * 64);
        #pragma unroll
        for (int i = 0; i < 4; ++i)
            reinterpret_cast<float4*>(ltile)[tid + i * 256] = src[tid + i * 256];

        // out_state tile (64 b x 64 c), coalesced along c
        #pragma unroll
        for (int i = 0; i < 4; ++i) {
            int idx = tid + i * 256;
            int bb = idx >> 4, c4 = (idx & 15) * 4;
            float4 v = *reinterpret_cast<const float4*>(
                &outs[((size_t)s * 64 + bb) * 256 + c0 + c4]);
            otile[bb*65 + c4+0] = v.x; otile[bb*65 + c4+1] = v.y;
            otile[bb*65 + c4+2] = v.z; otile[bb*65 + c4+3] = v.w;
        }
        __syncthreads();

        #pragma unroll
        for (int ci = 0; ci < 16; ++ci) {
            int c = wv * 16 + ci;
            float x = ltile[c * 64 + lane];
            float m = x;
            #pragma unroll
            for (int off = 32; off; off >>= 1)
                m = fmaxf(m, __shfl_xor(m, off));
            float e = __expf(x - m);
            float ssum = e;
            #pragma unroll
            for (int off = 32; off; off >>= 1)
                ssum += __shfl_xor(ssum, off);
            float attn = e / ssum;
            acc[ci] += attn * otile[lane * 65 + c];
        }
        __syncthreads();
    }

    #pragma unroll
    for (int ci = 0; ci < 16; ++ci) {
        int c = wv * 16 + ci;
        part[(size_t)sc * 16384 + (size_t)lane * 256 + c0 + c] = acc[ci];
    }
}

__global__ __launch_bounds__(256)
void reduce_part(const float* __restrict__ part, float* __restrict__ sent)
{
    int idx = blockIdx.x * 256 + threadIdx.x;   // 0..16383 = b*256+c
    float s = 0.f;
    for (int sc = 0; sc < 64; ++sc)
        s += part[(size_t)sc * 16384 + idx];
    sent[idx] = s;
}

// ---------------------------------------------------------------------------
extern "C" void kernel_launch(void* const* d_in, const int* in_sizes, int n_in,
                              void* d_out, int out_size, void* d_ws, size_t ws_size,
                              hipStream_t stream)
{
    const float* inp    = (const float*)d_in[0];
    const float* hid0   = (const float*)d_in[1];
    const float* w_ih_f = (const float*)d_in[2];
    const float* w_hh_f = (const float*)d_in[3];
    const float* b_ih_f = (const float*)d_in[4];
    const float* b_hh_f = (const float*)d_in[5];
    const float* w_ih_b = (const float*)d_in[6];
    const float* w_hh_b = (const float*)d_in[7];
    const float* b_ih_b = (const float*)d_in[8];
    const float* b_hh_b = (const float*)d_in[9];
    const float* attn_w = (const float*)d_in[10];
    const float* attn_b = (const float*)d_in[11];
    const float* comb_w = (const float*)d_in[12];

    float* out = (float*)d_out;   // [0,16384): sent, [16384,32768): hid_out

    char* ws = (char*)d_ws;
    const size_t XG_BYTES = (size_t)S_LEN * BATCH * 384 * 4;  // 201,326,592
    const size_t OS_BYTES = (size_t)S_LEN * BATCH * 256 * 4;  // 134,217,728
    if (ws_size < 2 * XG_BYTES + OS_BYTES) return;  // need 512 MiB scratch

    float* xg_f   = (float*)(ws);
    float* xg_b   = (float*)(ws + XG_BYTES);
    float* outs   = (float*)(ws + 2 * XG_BYTES);
    float* sa     = (float*)(ws);               // reuse xg_f (dead after scan)
    float* logits = (float*)(ws + XG_BYTES);    // reuse xg_b
    float* part   = (float*)(ws);               // reuse sa (dead after K4)

    const int M = S_LEN * BATCH;                // 131072
    dim3 blk(256);

    // K1: input-side gates, both directions (MFMA split-bf16)
    gemm_mfma<0><<<dim3(3, 1024), blk, 0, stream>>>(inp, w_ih_f, b_ih_f, xg_f, M, 384, 256);
    gemm_mfma<0><<<dim3(3, 1024), blk, 0, stream>>>(inp, w_ih_b, b_ih_b, xg_b, M, 384, 256);

    // K2: sequential bidirectional GRU (128 independent WGs, 256 thr each)
    gru_scan<<<dim3(128), dim3(256), 0, stream>>>(
        xg_f, xg_b, w_hh_f, w_hh_b, b_hh_f, b_hh_b, hid0, outs, out + 16384);

    // K3: sent_annotation = out_state @ attn_w^T + attn_b (MFMA)
    gemm_mfma<0><<<dim3(2, 1024), blk, 0, stream>>>(outs, attn_w, attn_b, sa, M, 256, 256);

    // K4: logits = sa @ comb_w^T, stored transposed (S,C,B) (MFMA)
    gemm_mfma<1><<<dim3(2, 1024), blk, 0, stream>>>(sa, comb_w, nullptr, logits, M, 256, 256);

    // K5: softmax over batch + weighted partial sum over s-chunks
    attn_reduce<<<dim3(4, 64), blk, 0, stream>>>(logits, outs, part);

    // K6: final reduction over s-chunks -> sent
    reduce_part<<<dim3(64), blk, 0, stream>>>(part, out);
}